// Round 3
// baseline (131.160 us; speedup 1.0000x reference)
//
#include <hip/hip_runtime.h>
#include <math.h>

#define BATCH 16384
#define EDIM 128
#define RD (128 * 128)
#define NREL 200
#define G 16                       // batch elements per score block
#define MAXDESC (BATCH / G + NREL) // 1224 upper bound on chunk count
#define HBLOCKS 64

// ---------------------------------------------------------------------------
// ws layout (32-bit words):
//  [0]              idx-dtype flag (1 => int64)
//  [1]              nblocks (number of chunk descriptors)
//  [2    .. 202)    counts[200]
//  [202  .. 402)    offsets[200]
//  [402  .. 602)    cursors[200]
//  [602  .. 802)    r2[200] (float)
//  [1024 .. 1024+MAXDESC)  desc[]  (rid<<24 | start<<8 | cnt)
//  [4096 .. 4096+BATCH)    sorted[] (batch ids grouped by relation)
//  [32768.. 32768+BATCH)   partial[] (float, per-element loss)
// ---------------------------------------------------------------------------

__device__ __forceinline__ int load_idx(const void* p, int b, int is64) {
    if (is64) return (int)((const long long*)p)[b];
    return ((const int*)p)[b];
}

// block 0: zero control words; block 1: detect index dtype
__global__ void init_kernel(const unsigned int* __restrict__ hh,
                            const unsigned int* __restrict__ rr,
                            const unsigned int* __restrict__ pp,
                            const unsigned int* __restrict__ nn,
                            unsigned int* __restrict__ ws) {
    if (blockIdx.x == 0) {
        for (int i = 1 + threadIdx.x; i < 602; i += 256) ws[i] = 0u;
    } else if (blockIdx.x == 1 && threadIdx.x == 0) {
        unsigned int orall = 0u;
        for (int i = 0; i < 256; ++i)
            orall |= hh[2 * i + 1] | rr[2 * i + 1] | pp[2 * i + 1] | nn[2 * i + 1];
        ws[0] = (orall == 0u) ? 1u : 0u;
    }
}

// blocks [0,HBLOCKS): relation histogram; blocks [HBLOCKS, HBLOCKS+NREL): r2
__global__ __launch_bounds__(256) void hist_rel_kernel(const void* __restrict__ rI,
                                                       const float* __restrict__ rel,
                                                       unsigned int* __restrict__ ws) {
    unsigned int* counts = ws + 2;
    float* r2 = (float*)(ws + 602);
    if (blockIdx.x < HBLOCKS) {
        const int is64 = (int)ws[0];
        for (int b = blockIdx.x * 256 + threadIdx.x; b < BATCH; b += HBLOCKS * 256) {
            int rid = load_idx(rI, b, is64);
            atomicAdd(&counts[rid], 1u);
        }
    } else {
        const int rid = blockIdx.x - HBLOCKS;
        const float4* row = (const float4*)(rel + (size_t)rid * RD);
        float acc = 0.f;
#pragma unroll
        for (int k = 0; k < 16; ++k) {
            float4 v = row[k * 256 + threadIdx.x];
            acc = fmaf(v.x, v.x, acc);
            acc = fmaf(v.y, v.y, acc);
            acc = fmaf(v.z, v.z, acc);
            acc = fmaf(v.w, v.w, acc);
        }
        for (int off = 32; off > 0; off >>= 1) acc += __shfl_down(acc, off, 64);
        __shared__ float sm[4];
        if ((threadIdx.x & 63) == 0) sm[threadIdx.x >> 6] = acc;
        __syncthreads();
        if (threadIdx.x == 0) r2[rid] = sm[0] + sm[1] + sm[2] + sm[3];
    }
}

// single block: exclusive scans (LDS) + emit chunk descriptors in parallel
__global__ __launch_bounds__(256) void scan_desc_kernel(unsigned int* __restrict__ ws) {
    __shared__ unsigned int cL[NREL], offL[NREL], chkL[NREL];
    unsigned int* counts = ws + 2;
    unsigned int* offsets = ws + 202;
    unsigned int* desc = ws + 1024;
    const int t = threadIdx.x;
    if (t < NREL) cL[t] = counts[t];
    __syncthreads();
    if (t == 0) {
        unsigned int off = 0, coff = 0;
        for (int i = 0; i < NREL; ++i) {
            offL[i] = off;
            chkL[i] = coff;
            off += cL[i];
            coff += (cL[i] + G - 1) / G;
        }
        ws[1] = coff; // nblocks
    }
    __syncthreads();
    if (t < NREL) {
        offsets[t] = offL[t];
        const unsigned int c = cL[t], o = offL[t], dpos = chkL[t];
        for (unsigned int ch = 0; ch * G < c; ++ch) {
            unsigned int cc = c - ch * G;
            if (cc > G) cc = G;
            desc[dpos + ch] = ((unsigned int)t << 24) | ((o + ch * G) << 8) | cc;
        }
    }
}

__global__ __launch_bounds__(256) void scatter_kernel(const void* __restrict__ rI,
                                                      unsigned int* __restrict__ ws) {
    const int is64 = (int)ws[0];
    unsigned int* offsets = ws + 202;
    unsigned int* cursors = ws + 402;
    unsigned int* sorted = ws + 4096;
    for (int b = blockIdx.x * 256 + threadIdx.x; b < BATCH; b += HBLOCKS * 256) {
        int rid = load_idx(rI, b, is64);
        unsigned int pos = offsets[rid] + atomicAdd(&cursors[rid], 1u);
        sorted[pos] = (unsigned int)b;
    }
}

// One block per (relation, chunk of up to G elements). Streams the 64KB
// relation row once and applies it to G head vectors held in LDS.
__global__ __launch_bounds__(256) void score_kernel(
    const void* __restrict__ hI, const void* __restrict__ pI, const void* __restrict__ nI,
    const float* __restrict__ ent, const float* __restrict__ rel,
    const unsigned int* __restrict__ ws, float* __restrict__ partial) {
    const unsigned int nb = ws[1];
    if (blockIdx.x >= nb) return;
    const unsigned int dsc = (ws + 1024)[blockIdx.x];
    const int rid = (int)(dsc >> 24);
    const int start = (int)((dsc >> 8) & 0xFFFFu);
    const int cnt = (int)(dsc & 0xFFu);
    const int is64 = (int)ws[0];
    const unsigned int* sorted = ws + 4096;
    const float* r2 = (const float*)(ws + 602);

    __shared__ __attribute__((aligned(16))) float h_lds[G][EDIM];
    __shared__ __attribute__((aligned(16))) float tp_lds[G][EDIM];
    __shared__ __attribute__((aligned(16))) float tn_lds[G][EDIM];
    __shared__ float e2_lds[G];
    __shared__ int sidx[G];
    __shared__ float red[2][4][G];

    const int t = threadIdx.x;
    // stage: 16 lanes per element g; lane l covers dims l*8 .. l*8+7
    {
        const int g = t >> 4, l = t & 15;
        float e2 = 0.f;
        if (g < cnt) {
            const int b = (int)sorted[start + g];
            if (l == 0) sidx[g] = b;
            const int hi = load_idx(hI, b, is64);
            const int pi = load_idx(pI, b, is64);
            const int ni = load_idx(nI, b, is64);
            const float4* hr = (const float4*)(ent + (size_t)hi * EDIM) + l * 2;
            const float4* pr = (const float4*)(ent + (size_t)pi * EDIM) + l * 2;
            const float4* nr = (const float4*)(ent + (size_t)ni * EDIM) + l * 2;
#pragma unroll
            for (int j = 0; j < 2; ++j) {
                float4 hv = hr[j], pv = pr[j], nv = nr[j];
                *(float4*)&h_lds[g][l * 8 + j * 4] = hv;
                *(float4*)&tp_lds[g][l * 8 + j * 4] = pv;
                *(float4*)&tn_lds[g][l * 8 + j * 4] = nv;
                e2 += hv.x * hv.x + hv.y * hv.y + hv.z * hv.z + hv.w * hv.w;
                e2 += pv.x * pv.x + pv.y * pv.y + pv.z * pv.z + pv.w * pv.w;
                e2 += nv.x * nv.x + nv.y * nv.y + nv.z * nv.z + nv.w * nv.w;
            }
        } else {
            if (l == 0) sidx[g] = -1;
            const float4 z = make_float4(0.f, 0.f, 0.f, 0.f);
#pragma unroll
            for (int j = 0; j < 2; ++j) {
                *(float4*)&h_lds[g][l * 8 + j * 4] = z;
                *(float4*)&tp_lds[g][l * 8 + j * 4] = z;
                *(float4*)&tn_lds[g][l * 8 + j * 4] = z;
            }
        }
        e2 += __shfl_xor(e2, 1, 64);
        e2 += __shfl_xor(e2, 2, 64);
        e2 += __shfl_xor(e2, 4, 64);
        e2 += __shfl_xor(e2, 8, 64);
        if (l == 0) e2_lds[g] = e2;
    }
    __syncthreads();

    // main: thread owns cols ebase..+3, walks rows d = 8k + rowsel
    const float* R = rel + (size_t)rid * RD;
    const int rowsel = t >> 5;
    const int ebase = (t & 31) * 4;
    float4 acc[G];
#pragma unroll
    for (int g = 0; g < G; ++g) acc[g] = make_float4(0.f, 0.f, 0.f, 0.f);
#pragma unroll
    for (int k = 0; k < 16; ++k) {
        const float4 rv = *(const float4*)(R + k * 1024 + t * 4);
        const int dd = 8 * k + rowsel;
#pragma unroll
        for (int g = 0; g < G; ++g) {
            const float hd = h_lds[g][dd];
            acc[g].x = fmaf(rv.x, hd, acc[g].x);
            acc[g].y = fmaf(rv.y, hd, acc[g].y);
            acc[g].z = fmaf(rv.z, hd, acc[g].z);
            acc[g].w = fmaf(rv.w, hd, acc[g].w);
        }
    }

    const int lane = t & 63, wave = t >> 6;
#pragma unroll
    for (int g = 0; g < G; ++g) {
        const float4 tp = *(const float4*)&tp_lds[g][ebase];
        const float4 tn = *(const float4*)&tn_lds[g][ebase];
        float dp = acc[g].x * tp.x + acc[g].y * tp.y + acc[g].z * tp.z + acc[g].w * tp.w;
        float dn = acc[g].x * tn.x + acc[g].y * tn.y + acc[g].z * tn.z + acc[g].w * tn.w;
        for (int off = 32; off > 0; off >>= 1) {
            dp += __shfl_down(dp, off, 64);
            dn += __shfl_down(dn, off, 64);
        }
        if (lane == 0) {
            red[0][wave][g] = dp;
            red[1][wave][g] = dn;
        }
    }
    __syncthreads();
    if (t < cnt) {
        const float SP = red[0][0][t] + red[0][1][t] + red[0][2][t] + red[0][3][t];
        const float SN = red[1][0][t] + red[1][1][t] + red[1][2][t] + red[1][3][t];
        const float x = SN - SP; // = neg_score - pos_score
        const float sploss = (x > 0.f) ? (x + log1pf(expf(-x))) : log1pf(expf(x));
        partial[sidx[t]] = sploss + 1e-5f * 0.5f * (e2_lds[t] + r2[rid]);
    }
}

__global__ __launch_bounds__(256) void reduce_kernel(const float* __restrict__ partial,
                                                     float* __restrict__ out) {
    float acc = 0.f;
    for (int i = threadIdx.x; i < BATCH; i += 256) acc += partial[i];
    for (int off = 32; off > 0; off >>= 1) acc += __shfl_down(acc, off, 64);
    __shared__ float sm[4];
    if ((threadIdx.x & 63) == 0) sm[threadIdx.x >> 6] = acc;
    __syncthreads();
    if (threadIdx.x == 0)
        out[0] = (sm[0] + sm[1] + sm[2] + sm[3]) * (1.0f / (float)BATCH);
}

extern "C" void kernel_launch(void* const* d_in, const int* in_sizes, int n_in,
                              void* d_out, int out_size, void* d_ws, size_t ws_size,
                              hipStream_t stream) {
    const void* h  = d_in[0];
    const void* r  = d_in[1];
    const void* pt = d_in[2];
    const void* nt = d_in[3];
    const float* ent = (const float*)d_in[4];
    const float* rel = (const float*)d_in[5];

    unsigned int* ws = (unsigned int*)d_ws;
    float* partial = (float*)(ws + 32768);

    init_kernel<<<2, 256, 0, stream>>>((const unsigned int*)h, (const unsigned int*)r,
                                       (const unsigned int*)pt, (const unsigned int*)nt, ws);
    hist_rel_kernel<<<HBLOCKS + NREL, 256, 0, stream>>>(r, rel, ws);
    scan_desc_kernel<<<1, 256, 0, stream>>>(ws);
    scatter_kernel<<<HBLOCKS, 256, 0, stream>>>(r, ws);
    score_kernel<<<MAXDESC, 256, 0, stream>>>(h, pt, nt, ent, rel, ws, partial);
    reduce_kernel<<<1, 256, 0, stream>>>(partial, (float*)d_out);
}

// Round 4
// 112.758 us; speedup vs baseline: 1.1632x; 1.1632x over previous
//
#include <hip/hip_runtime.h>
#include <math.h>

#define BATCH 16384
#define EDIM 128
#define RD (128 * 128)
#define NREL 200
#define G 16                       // batch elements per score block
#define MAXDESC (BATCH / G + NREL) // 1224 upper bound on chunk count
#define SBLOCKS 64                 // scatter blocks

// ---------------------------------------------------------------------------
// ws layout (32-bit words):
//  [0]              idx-dtype flag (1 => int64)
//  [1]              nblocks (number of chunk descriptors)
//  [2    .. 202)    counts[200]
//  [202  .. 402)    offsets[200]
//  [402  .. 602)    cursors[200]
//  [602  .. 802)    r2[200] (float)
//  [1024 .. 1024+MAXDESC)  desc[]  (rid<<24 | start<<8 | cnt)
//  [4096 .. 4096+BATCH)    sorted[] (batch ids grouped by relation)
//  [32768.. 32768+BATCH)   partial[] (float, per-element loss)
// ---------------------------------------------------------------------------

__device__ __forceinline__ int load_idx(const void* p, int b, int is64) {
    if (is64) return (int)((const long long*)p)[b];
    return ((const int*)p)[b];
}

// blocks [0,NREL): count occurrences of relation rid (no atomics, no pre-zero)
//                  + inline parallel int64/int32 detection (block 0 publishes it)
// blocks [NREL,2*NREL): per-relation sum of squares of the 16384-elem row
__global__ __launch_bounds__(256) void count_r2_kernel(
    const unsigned int* __restrict__ hh, const unsigned int* __restrict__ rr,
    const unsigned int* __restrict__ pp, const unsigned int* __restrict__ nn,
    const void* __restrict__ rI, const float* __restrict__ rel,
    unsigned int* __restrict__ ws) {
    const int t = threadIdx.x;
    if (blockIdx.x < NREL) {
        // parallel dtype detect: odd 32-bit words of first 256 elems, all 4 arrays
        unsigned int o = hh[2 * t + 1] | rr[2 * t + 1] | pp[2 * t + 1] | nn[2 * t + 1];
#pragma unroll
        for (int off = 32; off > 0; off >>= 1) o |= __shfl_xor(o, off, 64);
        __shared__ unsigned int ow[4];
        if ((t & 63) == 0) ow[t >> 6] = o;
        __syncthreads();
        const int is64 = ((ow[0] | ow[1] | ow[2] | ow[3]) == 0u) ? 1 : 0;

        const int rid = blockIdx.x;
        int c = 0;
        for (int i = t; i < BATCH; i += 256) c += (load_idx(rI, i, is64) == rid);
#pragma unroll
        for (int off = 32; off > 0; off >>= 1) c += __shfl_down(c, off, 64);
        __shared__ int cw[4];
        if ((t & 63) == 0) cw[t >> 6] = c;
        __syncthreads();
        if (t == 0) {
            ws[2 + rid] = (unsigned int)(cw[0] + cw[1] + cw[2] + cw[3]);
            if (rid == 0) ws[0] = (unsigned int)is64;
        }
    } else {
        const int rid = blockIdx.x - NREL;
        const float4* row = (const float4*)(rel + (size_t)rid * RD);
        float acc = 0.f;
#pragma unroll
        for (int k = 0; k < 16; ++k) {
            float4 v = row[k * 256 + t];
            acc = fmaf(v.x, v.x, acc);
            acc = fmaf(v.y, v.y, acc);
            acc = fmaf(v.z, v.z, acc);
            acc = fmaf(v.w, v.w, acc);
        }
        for (int off = 32; off > 0; off >>= 1) acc += __shfl_down(acc, off, 64);
        __shared__ float sm[4];
        if ((t & 63) == 0) sm[t >> 6] = acc;
        __syncthreads();
        if (t == 0) ((float*)(ws + 602))[rid] = sm[0] + sm[1] + sm[2] + sm[3];
    }
}

// single block: parallel Hillis-Steele scans + descriptor emission + cursor zero
__global__ __launch_bounds__(256) void scan_desc_kernel(unsigned int* __restrict__ ws) {
    unsigned int* counts = ws + 2;
    unsigned int* offsets = ws + 202;
    unsigned int* cursors = ws + 402;
    unsigned int* desc = ws + 1024;
    __shared__ unsigned int s0[256], s1[256], c0[256], c1[256];
    const int t = threadIdx.x;
    const unsigned int cv = (t < NREL) ? counts[t] : 0u;
    const unsigned int kv = (cv + G - 1) / G;
    s0[t] = cv;
    c0[t] = kv;
    __syncthreads();
    unsigned int *pa = s0, *pb = s1, *qa = c0, *qb = c1;
    for (int off = 1; off < 256; off <<= 1) {
        const unsigned int va = pa[t] + ((t >= off) ? pa[t - off] : 0u);
        const unsigned int vb = qa[t] + ((t >= off) ? qa[t - off] : 0u);
        pb[t] = va;
        qb[t] = vb;
        __syncthreads();
        unsigned int* tmp = pa; pa = pb; pb = tmp;
        tmp = qa; qa = qb; qb = tmp;
    }
    if (t == 255) ws[1] = qa[255]; // total chunk count
    if (t < NREL) {
        const unsigned int excl = pa[t] - cv;
        const unsigned int cexcl = qa[t] - kv;
        offsets[t] = excl;
        cursors[t] = 0u;
        for (unsigned int ch = 0; ch * G < cv; ++ch) {
            unsigned int cc = cv - ch * G;
            if (cc > G) cc = G;
            desc[cexcl + ch] = ((unsigned int)t << 24) | ((excl + ch * G) << 8) | cc;
        }
    }
}

__global__ __launch_bounds__(256) void scatter_kernel(const void* __restrict__ rI,
                                                      unsigned int* __restrict__ ws) {
    const int is64 = (int)ws[0];
    unsigned int* offsets = ws + 202;
    unsigned int* cursors = ws + 402;
    unsigned int* sorted = ws + 4096;
    for (int b = blockIdx.x * 256 + threadIdx.x; b < BATCH; b += SBLOCKS * 256) {
        int rid = load_idx(rI, b, is64);
        unsigned int pos = offsets[rid] + atomicAdd(&cursors[rid], 1u);
        sorted[pos] = (unsigned int)b;
    }
}

// One block per (relation, chunk of up to G elements). Streams the 64KB
// relation row once; h held transposed in LDS so the inner loop reads
// 16 h-values with 4x ds_read_b128.
__global__ __launch_bounds__(256) void score_kernel(
    const void* __restrict__ hI, const void* __restrict__ pI, const void* __restrict__ nI,
    const float* __restrict__ ent, const float* __restrict__ rel,
    const unsigned int* __restrict__ ws, float* __restrict__ partial) {
    const unsigned int nb = ws[1];
    if (blockIdx.x >= nb) return;
    const unsigned int dsc = (ws + 1024)[blockIdx.x];
    const int rid = (int)(dsc >> 24);
    const int start = (int)((dsc >> 8) & 0xFFFFu);
    const int cnt = (int)(dsc & 0xFFu);
    const int is64 = (int)ws[0];
    const unsigned int* sorted = ws + 4096;
    const float* r2 = (const float*)(ws + 602);

    __shared__ __attribute__((aligned(16))) float hT[EDIM][G];  // [d][g]
    __shared__ __attribute__((aligned(16))) float tp_lds[G][EDIM];
    __shared__ __attribute__((aligned(16))) float tn_lds[G][EDIM];
    __shared__ float e2_lds[G];
    __shared__ int sidx[G];
    __shared__ float red[2][4][G];

    const int t = threadIdx.x;
    // stage: 16 lanes per element g; lane l covers dims l*8 .. l*8+7
    {
        const int g = t >> 4, l = t & 15;
        float e2 = 0.f;
        if (g < cnt) {
            const int b = (int)sorted[start + g];
            if (l == 0) sidx[g] = b;
            const int hi = load_idx(hI, b, is64);
            const int pi = load_idx(pI, b, is64);
            const int ni = load_idx(nI, b, is64);
            const float4* hr = (const float4*)(ent + (size_t)hi * EDIM) + l * 2;
            const float4* pr = (const float4*)(ent + (size_t)pi * EDIM) + l * 2;
            const float4* nr = (const float4*)(ent + (size_t)ni * EDIM) + l * 2;
#pragma unroll
            for (int j = 0; j < 2; ++j) {
                const float4 hv = hr[j], pv = pr[j], nv = nr[j];
                const int d0 = l * 8 + j * 4;
                hT[d0 + 0][g] = hv.x;
                hT[d0 + 1][g] = hv.y;
                hT[d0 + 2][g] = hv.z;
                hT[d0 + 3][g] = hv.w;
                *(float4*)&tp_lds[g][d0] = pv;
                *(float4*)&tn_lds[g][d0] = nv;
                e2 += hv.x * hv.x + hv.y * hv.y + hv.z * hv.z + hv.w * hv.w;
                e2 += pv.x * pv.x + pv.y * pv.y + pv.z * pv.z + pv.w * pv.w;
                e2 += nv.x * nv.x + nv.y * nv.y + nv.z * nv.z + nv.w * nv.w;
            }
        } else {
            const float4 z = make_float4(0.f, 0.f, 0.f, 0.f);
#pragma unroll
            for (int j = 0; j < 2; ++j) {
                const int d0 = l * 8 + j * 4;
                hT[d0 + 0][g] = 0.f;
                hT[d0 + 1][g] = 0.f;
                hT[d0 + 2][g] = 0.f;
                hT[d0 + 3][g] = 0.f;
                *(float4*)&tp_lds[g][d0] = z;
                *(float4*)&tn_lds[g][d0] = z;
            }
        }
        e2 += __shfl_xor(e2, 1, 64);
        e2 += __shfl_xor(e2, 2, 64);
        e2 += __shfl_xor(e2, 4, 64);
        e2 += __shfl_xor(e2, 8, 64);
        if (l == 0) e2_lds[g] = e2;
    }
    __syncthreads();

    // main: thread owns cols ebase..+3, walks rows d = 8k + rowsel
    const float* R = rel + (size_t)rid * RD;
    const int rowsel = t >> 5;
    const int ebase = (t & 31) * 4;
    float4 acc[G];
#pragma unroll
    for (int g = 0; g < G; ++g) acc[g] = make_float4(0.f, 0.f, 0.f, 0.f);
#pragma unroll
    for (int k = 0; k < 16; ++k) {
        const float4 rv = *(const float4*)(R + k * 1024 + t * 4);
        const int dd = 8 * k + rowsel;
        const float4* hp = (const float4*)&hT[dd][0];
#pragma unroll
        for (int q = 0; q < 4; ++q) {
            const float4 h4 = hp[q];
            acc[4 * q + 0].x = fmaf(rv.x, h4.x, acc[4 * q + 0].x);
            acc[4 * q + 0].y = fmaf(rv.y, h4.x, acc[4 * q + 0].y);
            acc[4 * q + 0].z = fmaf(rv.z, h4.x, acc[4 * q + 0].z);
            acc[4 * q + 0].w = fmaf(rv.w, h4.x, acc[4 * q + 0].w);
            acc[4 * q + 1].x = fmaf(rv.x, h4.y, acc[4 * q + 1].x);
            acc[4 * q + 1].y = fmaf(rv.y, h4.y, acc[4 * q + 1].y);
            acc[4 * q + 1].z = fmaf(rv.z, h4.y, acc[4 * q + 1].z);
            acc[4 * q + 1].w = fmaf(rv.w, h4.y, acc[4 * q + 1].w);
            acc[4 * q + 2].x = fmaf(rv.x, h4.z, acc[4 * q + 2].x);
            acc[4 * q + 2].y = fmaf(rv.y, h4.z, acc[4 * q + 2].y);
            acc[4 * q + 2].z = fmaf(rv.z, h4.z, acc[4 * q + 2].z);
            acc[4 * q + 2].w = fmaf(rv.w, h4.z, acc[4 * q + 2].w);
            acc[4 * q + 3].x = fmaf(rv.x, h4.w, acc[4 * q + 3].x);
            acc[4 * q + 3].y = fmaf(rv.y, h4.w, acc[4 * q + 3].y);
            acc[4 * q + 3].z = fmaf(rv.z, h4.w, acc[4 * q + 3].z);
            acc[4 * q + 3].w = fmaf(rv.w, h4.w, acc[4 * q + 3].w);
        }
    }

    const int lane = t & 63, wave = t >> 6;
#pragma unroll
    for (int g = 0; g < G; ++g) {
        const float4 tp = *(const float4*)&tp_lds[g][ebase];
        const float4 tn = *(const float4*)&tn_lds[g][ebase];
        float dp = acc[g].x * tp.x + acc[g].y * tp.y + acc[g].z * tp.z + acc[g].w * tp.w;
        float dn = acc[g].x * tn.x + acc[g].y * tn.y + acc[g].z * tn.z + acc[g].w * tn.w;
        for (int off = 32; off > 0; off >>= 1) {
            dp += __shfl_down(dp, off, 64);
            dn += __shfl_down(dn, off, 64);
        }
        if (lane == 0) {
            red[0][wave][g] = dp;
            red[1][wave][g] = dn;
        }
    }
    __syncthreads();
    if (t < cnt) {
        const float SP = red[0][0][t] + red[0][1][t] + red[0][2][t] + red[0][3][t];
        const float SN = red[1][0][t] + red[1][1][t] + red[1][2][t] + red[1][3][t];
        const float x = SN - SP; // = neg_score - pos_score
        const float sploss = (x > 0.f) ? (x + log1pf(expf(-x))) : log1pf(expf(x));
        partial[sidx[t]] = sploss + 1e-5f * 0.5f * (e2_lds[t] + r2[rid]);
    }
}

__global__ __launch_bounds__(256) void reduce_kernel(const float* __restrict__ partial,
                                                     float* __restrict__ out) {
    float acc = 0.f;
    for (int i = threadIdx.x; i < BATCH; i += 256) acc += partial[i];
    for (int off = 32; off > 0; off >>= 1) acc += __shfl_down(acc, off, 64);
    __shared__ float sm[4];
    if ((threadIdx.x & 63) == 0) sm[threadIdx.x >> 6] = acc;
    __syncthreads();
    if (threadIdx.x == 0)
        out[0] = (sm[0] + sm[1] + sm[2] + sm[3]) * (1.0f / (float)BATCH);
}

extern "C" void kernel_launch(void* const* d_in, const int* in_sizes, int n_in,
                              void* d_out, int out_size, void* d_ws, size_t ws_size,
                              hipStream_t stream) {
    const void* h  = d_in[0];
    const void* r  = d_in[1];
    const void* pt = d_in[2];
    const void* nt = d_in[3];
    const float* ent = (const float*)d_in[4];
    const float* rel = (const float*)d_in[5];

    unsigned int* ws = (unsigned int*)d_ws;
    float* partial = (float*)(ws + 32768);

    count_r2_kernel<<<2 * NREL, 256, 0, stream>>>(
        (const unsigned int*)h, (const unsigned int*)r,
        (const unsigned int*)pt, (const unsigned int*)nt, r, rel, ws);
    scan_desc_kernel<<<1, 256, 0, stream>>>(ws);
    scatter_kernel<<<SBLOCKS, 256, 0, stream>>>(r, ws);
    score_kernel<<<MAXDESC, 256, 0, stream>>>(h, pt, nt, ent, rel, ws, partial);
    reduce_kernel<<<1, 256, 0, stream>>>(partial, (float*)d_out);
}

// Round 6
// 90.654 us; speedup vs baseline: 1.4468x; 1.2438x over previous
//
#include <hip/hip_runtime.h>
#include <math.h>

#define BATCH 16384
#define EDIM 128
#define RD (128 * 128)
#define NREL 200
#define G 16
#define MAXDESC (BATCH / G + NREL) // 1224
#define SB 64                      // sort blocks
#define NTHR 256

// ---------------------------------------------------------------------------
// ws layout (32-bit words):
//  [400  .. 600)            r2[200] (float)
//  [1024 .. 1024+BATCH)     sorted[] (batch ids grouped by relation)
//  [20480.. 20480+MAXDESC)  desc[]  (rid<<24 | start<<8 | cnt; ~0u = sentinel)
// ---------------------------------------------------------------------------

__device__ __forceinline__ int load_idx(const void* p, int b, int is64) {
    if (is64) return (int)((const long long*)p)[b];
    return ((const int*)p)[b];
}

// blocks [0,SB): deterministic atomic-free counting sort of the batch by rid.
//   Each block: full 200-bin histogram (LDS atomics) + exclusive scan +
//   prefix counts for its slice + in-slice ranks -> scatter 256 elements.
//   Block 0 also emits desc[] and zeroes out[0].
// blocks [SB, SB+NREL): per-relation sum-of-squares r2.
__global__ __launch_bounds__(NTHR) void prep_kernel(
    const void* __restrict__ hI, const void* __restrict__ rI,
    const void* __restrict__ pI, const void* __restrict__ nI,
    const float* __restrict__ rel, unsigned int* __restrict__ ws,
    float* __restrict__ out) {
    const int t = threadIdx.x;
    const int bid = blockIdx.x;

    __shared__ unsigned int hist_all[256], hist_pre[256], offs[256], rloc[256];
    __shared__ unsigned int sA[256], sB[256];
    __shared__ unsigned int um4[4];
    __shared__ float sm4[4];

    if (bid >= SB) {
        // ---- r2 blocks ----
        const int rid = bid - SB;
        const float4* row = (const float4*)(rel + (size_t)rid * RD);
        float acc = 0.f;
#pragma unroll
        for (int k = 0; k < 16; ++k) {
            float4 v = row[k * 256 + t];
            acc = fmaf(v.x, v.x, acc);
            acc = fmaf(v.y, v.y, acc);
            acc = fmaf(v.z, v.z, acc);
            acc = fmaf(v.w, v.w, acc);
        }
        for (int off = 32; off > 0; off >>= 1) acc += __shfl_down(acc, off, 64);
        if ((t & 63) == 0) sm4[t >> 6] = acc;
        __syncthreads();
        if (t == 0) ((float*)(ws + 400))[rid] = sm4[0] + sm4[1] + sm4[2] + sm4[3];
        return;
    }

    // ---- dtype detect (per block, redundant) ----
    {
        unsigned int o = ((const unsigned int*)hI)[2 * t + 1] |
                         ((const unsigned int*)rI)[2 * t + 1] |
                         ((const unsigned int*)pI)[2 * t + 1] |
                         ((const unsigned int*)nI)[2 * t + 1];
#pragma unroll
        for (int off = 32; off > 0; off >>= 1) o |= __shfl_xor(o, off, 64);
        if ((t & 63) == 0) um4[t >> 6] = o;
    }
    hist_all[t] = 0u;
    hist_pre[t] = 0u;
    __syncthreads();
    const int is64 = ((um4[0] | um4[1] | um4[2] | um4[3]) == 0u) ? 1 : 0;

    // ---- histogram pass (full array) + prefix histogram + own-slice rids ----
    const int base = bid * NTHR;
    for (int i = t; i < BATCH; i += NTHR) {
        const int q = load_idx(rI, i, is64);
        atomicAdd(&hist_all[q], 1u);
        if (i < base) atomicAdd(&hist_pre[q], 1u);
        if ((i >> 8) == bid) rloc[t] = (unsigned int)q;
    }
    __syncthreads();

    // ---- inclusive scan of hist_all -> exclusive offsets ----
    sA[t] = hist_all[t];
    __syncthreads();
    {
        unsigned int *pa = sA, *pb = sB;
        for (int off = 1; off < 256; off <<= 1) {
            const unsigned int v = pa[t] + ((t >= off) ? pa[t - off] : 0u);
            pb[t] = v;
            __syncthreads();
            unsigned int* tm = pa; pa = pb; pb = tm;
        }
        offs[t] = pa[t] - hist_all[t];
    }
    __syncthreads();

    // ---- in-slice rank + deterministic scatter ----
    {
        const unsigned int q = rloc[t];
        int rank = 0;
        for (int j = 0; j < t; ++j) rank += (rloc[j] == q);
        const unsigned int pos = offs[q] + hist_pre[q] + (unsigned int)rank;
        ws[1024 + pos] = (unsigned int)(base + t);
    }

    // ---- block 0: descriptor emission + out zero ----
    if (bid == 0) {
        if (t == 0) out[0] = 0.f;
        for (int d = t; d < MAXDESC; d += NTHR) ws[20480 + d] = ~0u;
        __syncthreads();
        // scan of per-relation chunk counts
        const unsigned int cv = hist_all[t];
        const unsigned int kv = (cv + G - 1) / G;
        sA[t] = kv;
        __syncthreads();
        unsigned int *pa = sA, *pb = sB;
        for (int off = 1; off < 256; off <<= 1) {
            const unsigned int v = pa[t] + ((t >= off) ? pa[t - off] : 0u);
            pb[t] = v;
            __syncthreads();
            unsigned int* tm = pa; pa = pb; pb = tm;
        }
        const unsigned int cex = pa[t] - kv;
        if (t < NREL) {
            const unsigned int my_off = offs[t];
            for (unsigned int ch = 0; ch * G < cv; ++ch) {
                unsigned int cc = cv - ch * G;
                if (cc > G) cc = G;
                ws[20480 + cex + ch] =
                    ((unsigned int)t << 24) | ((my_off + ch * G) << 8) | cc;
            }
        }
    }
}

// One block per chunk descriptor. Streams the 64KB relation row once and
// applies it to up to G head vectors; accumulates chunk loss into out[0].
__global__ __launch_bounds__(NTHR) void score_kernel(
    const void* __restrict__ hI, const void* __restrict__ rI,
    const void* __restrict__ pI, const void* __restrict__ nI,
    const float* __restrict__ ent, const float* __restrict__ rel,
    const unsigned int* __restrict__ ws, float* __restrict__ out) {
    const unsigned int dsc = ws[20480 + blockIdx.x];
    if (dsc == ~0u) return;
    const int rid = (int)(dsc >> 24);
    const int start = (int)((dsc >> 8) & 0xFFFFu);
    const int cc = (int)(dsc & 0xFFu);
    const int t = threadIdx.x;

    __shared__ __attribute__((aligned(16))) float hT[EDIM][G];  // [d][g]
    __shared__ __attribute__((aligned(16))) float tp[G][EDIM];
    __shared__ __attribute__((aligned(16))) float tn[G][EDIM];
    __shared__ float e2a[G];
    __shared__ float red[2][4][G];
    __shared__ unsigned int um4[4];

    // dtype detect (per block, redundant)
    {
        unsigned int o = ((const unsigned int*)hI)[2 * t + 1] |
                         ((const unsigned int*)rI)[2 * t + 1] |
                         ((const unsigned int*)pI)[2 * t + 1] |
                         ((const unsigned int*)nI)[2 * t + 1];
#pragma unroll
        for (int off = 32; off > 0; off >>= 1) o |= __shfl_xor(o, off, 64);
        if ((t & 63) == 0) um4[t >> 6] = o;
        __syncthreads();
    }
    const int is64 = ((um4[0] | um4[1] | um4[2] | um4[3]) == 0u) ? 1 : 0;

    // stage: 16 lanes per element g; lane l covers dims l*8 .. l*8+7
    {
        const int g = t >> 4, l = t & 15;
        float e2 = 0.f;
        if (g < cc) {
            const int b = (int)ws[1024 + start + g];
            const int hi = load_idx(hI, b, is64);
            const int pi = load_idx(pI, b, is64);
            const int ni = load_idx(nI, b, is64);
            const float4* hr = (const float4*)(ent + (size_t)hi * EDIM) + l * 2;
            const float4* pr = (const float4*)(ent + (size_t)pi * EDIM) + l * 2;
            const float4* nr = (const float4*)(ent + (size_t)ni * EDIM) + l * 2;
#pragma unroll
            for (int j = 0; j < 2; ++j) {
                const float4 hv = hr[j], pv = pr[j], nv = nr[j];
                const int d0 = l * 8 + j * 4;
                hT[d0 + 0][g] = hv.x;
                hT[d0 + 1][g] = hv.y;
                hT[d0 + 2][g] = hv.z;
                hT[d0 + 3][g] = hv.w;
                *(float4*)&tp[g][d0] = pv;
                *(float4*)&tn[g][d0] = nv;
                e2 += hv.x * hv.x + hv.y * hv.y + hv.z * hv.z + hv.w * hv.w;
                e2 += pv.x * pv.x + pv.y * pv.y + pv.z * pv.z + pv.w * pv.w;
                e2 += nv.x * nv.x + nv.y * nv.y + nv.z * nv.z + nv.w * nv.w;
            }
        } else {
            const float4 z = make_float4(0.f, 0.f, 0.f, 0.f);
#pragma unroll
            for (int j = 0; j < 2; ++j) {
                const int d0 = l * 8 + j * 4;
                hT[d0 + 0][g] = 0.f;
                hT[d0 + 1][g] = 0.f;
                hT[d0 + 2][g] = 0.f;
                hT[d0 + 3][g] = 0.f;
                *(float4*)&tp[g][d0] = z;
                *(float4*)&tn[g][d0] = z;
            }
        }
        e2 += __shfl_xor(e2, 1, 64);
        e2 += __shfl_xor(e2, 2, 64);
        e2 += __shfl_xor(e2, 4, 64);
        e2 += __shfl_xor(e2, 8, 64);
        if (l == 0) e2a[g] = e2;
    }
    __syncthreads();

    // main: thread owns cols ebase..+3, walks rows d = 8k + rowsel
    const float* R = rel + (size_t)rid * RD;
    const int rowsel = t >> 5;
    const int ebase = (t & 31) * 4;
    float4 acc[G];
#pragma unroll
    for (int g = 0; g < G; ++g) acc[g] = make_float4(0.f, 0.f, 0.f, 0.f);
#pragma unroll
    for (int k = 0; k < 16; ++k) {
        const float4 rv = *(const float4*)(R + k * 1024 + t * 4);
        const int dd = 8 * k + rowsel;
        const float4* hp = (const float4*)&hT[dd][0];
#pragma unroll
        for (int q = 0; q < 4; ++q) {
            const float4 h4 = hp[q];
            acc[4 * q + 0].x = fmaf(rv.x, h4.x, acc[4 * q + 0].x);
            acc[4 * q + 0].y = fmaf(rv.y, h4.x, acc[4 * q + 0].y);
            acc[4 * q + 0].z = fmaf(rv.z, h4.x, acc[4 * q + 0].z);
            acc[4 * q + 0].w = fmaf(rv.w, h4.x, acc[4 * q + 0].w);
            acc[4 * q + 1].x = fmaf(rv.x, h4.y, acc[4 * q + 1].x);
            acc[4 * q + 1].y = fmaf(rv.y, h4.y, acc[4 * q + 1].y);
            acc[4 * q + 1].z = fmaf(rv.z, h4.y, acc[4 * q + 1].z);
            acc[4 * q + 1].w = fmaf(rv.w, h4.y, acc[4 * q + 1].w);
            acc[4 * q + 2].x = fmaf(rv.x, h4.z, acc[4 * q + 2].x);
            acc[4 * q + 2].y = fmaf(rv.y, h4.z, acc[4 * q + 2].y);
            acc[4 * q + 2].z = fmaf(rv.z, h4.z, acc[4 * q + 2].z);
            acc[4 * q + 2].w = fmaf(rv.w, h4.z, acc[4 * q + 2].w);
            acc[4 * q + 3].x = fmaf(rv.x, h4.w, acc[4 * q + 3].x);
            acc[4 * q + 3].y = fmaf(rv.y, h4.w, acc[4 * q + 3].y);
            acc[4 * q + 3].z = fmaf(rv.z, h4.w, acc[4 * q + 3].z);
            acc[4 * q + 3].w = fmaf(rv.w, h4.w, acc[4 * q + 3].w);
        }
    }

    const int lane = t & 63, wave = t >> 6;
#pragma unroll
    for (int g = 0; g < G; ++g) {
        const float4 tpv = *(const float4*)&tp[g][ebase];
        const float4 tnv = *(const float4*)&tn[g][ebase];
        float dp = acc[g].x * tpv.x + acc[g].y * tpv.y + acc[g].z * tpv.z + acc[g].w * tpv.w;
        float dn = acc[g].x * tnv.x + acc[g].y * tnv.y + acc[g].z * tnv.z + acc[g].w * tnv.w;
        for (int off = 32; off > 0; off >>= 1) {
            dp += __shfl_down(dp, off, 64);
            dn += __shfl_down(dn, off, 64);
        }
        if (lane == 0) {
            red[0][wave][g] = dp;
            red[1][wave][g] = dn;
        }
    }
    __syncthreads();

    float s = 0.f;
    if (t < cc) {
        const float SP = red[0][0][t] + red[0][1][t] + red[0][2][t] + red[0][3][t];
        const float SN = red[1][0][t] + red[1][1][t] + red[1][2][t] + red[1][3][t];
        const float x = SN - SP; // neg_score - pos_score
        const float sploss = (x > 0.f) ? (x + log1pf(expf(-x))) : log1pf(expf(x));
        const float r2v = ((const float*)(ws + 400))[rid];
        s = sploss + 1e-5f * 0.5f * (e2a[t] + r2v);
    }
    if (t < 64) {
#pragma unroll
        for (int off = 32; off > 0; off >>= 1) s += __shfl_down(s, off, 64);
        if (t == 0) atomicAdd(out, s * (1.0f / (float)BATCH));
    }
}

extern "C" void kernel_launch(void* const* d_in, const int* in_sizes, int n_in,
                              void* d_out, int out_size, void* d_ws, size_t ws_size,
                              hipStream_t stream) {
    const void* h = d_in[0];
    const void* r = d_in[1];
    const void* pt = d_in[2];
    const void* nt = d_in[3];
    const float* ent = (const float*)d_in[4];
    const float* rel = (const float*)d_in[5];
    unsigned int* ws = (unsigned int*)d_ws;
    float* outp = (float*)d_out;

    prep_kernel<<<SB + NREL, NTHR, 0, stream>>>(h, r, pt, nt, rel, ws, outp);
    score_kernel<<<MAXDESC, NTHR, 0, stream>>>(h, r, pt, nt, ent, rel, ws, outp);
}